// Round 7
// baseline (294.989 us; speedup 1.0000x reference)
//
#include <hip/hip_runtime.h>
#include <hip/hip_bf16.h>
#include <stdint.h>

typedef __attribute__((ext_vector_type(8))) short short8;
typedef __attribute__((ext_vector_type(4))) short bf4;
typedef __attribute__((ext_vector_type(4))) float f32x4;

#define B_ 2
#define N1 2048
#define N2 256
#define NT 2304
#define D_ 1024
#define H_ 16
#define HD 64
// attention scale folded into Q: hd^-0.5 * log2(e)
#define QSCALE 0.18033688011112042f
#define RESCALE_THR 8.0f

static __device__ __forceinline__ float bf2f(short s){
  union { unsigned int u; float f; } u;
  u.u = ((unsigned int)(unsigned short)s) << 16;
  return u.f;
}
// round-to-nearest-even f32 -> bf16 (finite inputs)
static __device__ __forceinline__ short f2bf(float f){
  union { float f; unsigned int u; } v; v.f = f;
  unsigned int u = v.u;
  unsigned int lsb = (u >> 16) & 1u;
  u += 0x7fffu + lsb;
  return (short)(u >> 16);
}
static __device__ __forceinline__ unsigned int pack2(short a, short b){
  return (unsigned int)(unsigned short)a | (((unsigned int)(unsigned short)b) << 16);
}

static __device__ __forceinline__ float fexp2(float x){
#if __has_builtin(__builtin_amdgcn_exp2f)
  return __builtin_amdgcn_exp2f(x);
#else
  return exp2f(x);
#endif
}

static __device__ __forceinline__ void gload16(const void* g, void* l){
  __builtin_amdgcn_global_load_lds(
      (const __attribute__((address_space(1))) void*)g,
      (__attribute__((address_space(3))) void*)l, 16, 0, 0);
}

// ---------------- fp32 -> bf16 convert ----------------
__global__ __launch_bounds__(256) void k_cvt_bf16(const float* __restrict__ in,
                                                  short* __restrict__ out, int n){
  int i = (blockIdx.x * 256 + threadIdx.x) * 8;
  if (i >= n) return;
  float4 a = *(const float4*)(in + i);
  float4 b = *(const float4*)(in + i + 4);
  short8 o;
  o[0]=f2bf(a.x); o[1]=f2bf(a.y); o[2]=f2bf(a.z); o[3]=f2bf(a.w);
  o[4]=f2bf(b.x); o[5]=f2bf(b.y); o[6]=f2bf(b.z); o[7]=f2bf(b.w);
  *(short8*)(out + i) = o;
}

// ---------------- W (K x N, f32) -> Wt (N x K, bf16) ----------------
__global__ __launch_bounds__(256) void k_transpose_w(const float* __restrict__ W,
                                                     short* __restrict__ Wt,
                                                     int K, int N){
  __shared__ float tl[64][65];
  const int n0 = blockIdx.x * 64, k0 = blockIdx.y * 64;
  const int t = threadIdx.x, r = t >> 2, c = (t & 3) * 16;
  const float* src = W + (size_t)(k0 + r) * N + n0 + c;
  #pragma unroll
  for (int i = 0; i < 16; i += 4){
    float4 v = *(const float4*)(src + i);
    tl[r][c+i] = v.x; tl[r][c+i+1] = v.y; tl[r][c+i+2] = v.z; tl[r][c+i+3] = v.w;
  }
  __syncthreads();
  short8 o0, o1;
  #pragma unroll
  for (int i = 0; i < 8; i++) o0[i] = f2bf(tl[c+i][r]);
  #pragma unroll
  for (int i = 0; i < 8; i++) o1[i] = f2bf(tl[c+8+i][r]);
  short* dst = Wt + (size_t)(n0 + r) * K + k0 + c;
  *(short8*)(dst)     = o0;
  *(short8*)(dst + 8) = o1;
}

// ---------------- GEMM: C[M,N] = A[M,K] * Bt[N,K]^T + bias ----------------
template<int OUT_BF16>
__global__ __launch_bounds__(256) void k_gemm_bt(const short* __restrict__ A,
                                                 const short* __restrict__ Bt,
                                                 const float* __restrict__ bias,
                                                 void* __restrict__ Cp,
                                                 int M, int N, int K){
  __shared__ __align__(16) short As[128*32];
  __shared__ __align__(16) short Bs[128*32];
  const int t = threadIdx.x;
  const int w = t >> 6, l = t & 63;
  const int lc = l & 15, g = l >> 4;
  const int tm = blockIdx.y * 128, tn = blockIdx.x * 128;
  const int wm = (w >> 1) * 64, wn = (w & 1) * 64;

  const int r0 = w*32 + (l >> 2);
  const int r1 = r0 + 16;
  const int cb = (l & 3) * 16;

  const char* Ag0 = (const char*)(A + (size_t)(tm + r0) * K) + cb;
  const char* Ag1 = (const char*)(A + (size_t)(tm + r1) * K) + cb;
  const char* Bg0 = (const char*)(Bt + (size_t)(tn + r0) * K) + cb;
  const char* Bg1 = (const char*)(Bt + (size_t)(tn + r1) * K) + cb;
  char* Al0 = (char*)As + (w*2  )*1024;
  char* Al1 = (char*)As + (w*2+1)*1024;
  char* Bl0 = (char*)Bs + (w*2  )*1024;
  char* Bl1 = (char*)Bs + (w*2+1)*1024;

  f32x4 acc[4][4];
  #pragma unroll
  for (int m=0;m<4;m++){
    #pragma unroll
    for (int n=0;n<4;n++){ acc[m][n][0]=0.f; acc[m][n][1]=0.f; acc[m][n][2]=0.f; acc[m][n][3]=0.f; }
  }

  for (int k0 = 0; k0 < K; k0 += 32){
    const int kb = k0 * 2;
    gload16(Ag0 + kb, Al0);
    gload16(Ag1 + kb, Al1);
    gload16(Bg0 + kb, Bl0);
    gload16(Bg1 + kb, Bl1);
    __syncthreads();
    short8 af[4], bfr[4];
    #pragma unroll
    for (int m=0;m<4;m++) af[m]  = *(const short8*)(As + (wm + m*16 + lc)*32 + g*8);
    #pragma unroll
    for (int n=0;n<4;n++) bfr[n] = *(const short8*)(Bs + (wn + n*16 + lc)*32 + g*8);
    #pragma unroll
    for (int m=0;m<4;m++){
      #pragma unroll
      for (int n=0;n<4;n++)
        acc[m][n] = __builtin_amdgcn_mfma_f32_16x16x32_bf16(af[m], bfr[n], acc[m][n], 0, 0, 0);
    }
    __syncthreads();
  }

  #pragma unroll
  for (int n=0;n<4;n++){
    const int col = tn + wn + n*16 + lc;
    const float bv = bias[col];
    #pragma unroll
    for (int m=0;m<4;m++){
      const int row = tm + wm + m*16 + g*4;
      #pragma unroll
      for (int r=0;r<4;r++){
        float v = acc[m][n][r] + bv;
        if (OUT_BF16) ((short*)Cp)[(size_t)(row + r)*N + col] = f2bf(v);
        else          ((float*)Cp)[(size_t)(row + r)*N + col] = v;
      }
    }
  }
}

// ---------------- per-head LN (+ optional RoPE), shuffle-free -------------
// One THREAD per (b,h,n) row: 64 bf16 q/k/v held in regs, mean/var as
// in-register sums, w/b via uniform scalar loads. n-innermost across
// threads -> output writes fully coalesced (128B/thread contiguous).
__global__ __launch_bounds__(256) void k_lnrope(const short* __restrict__ qkv,
    const float* __restrict__ qw, const float* __restrict__ qb,
    const float* __restrict__ kw, const float* __restrict__ kb,
    const float* __restrict__ fcos, const float* __restrict__ fsin,
    short* __restrict__ Qo, short* __restrict__ Ko, short* __restrict__ Vo,
    int Nseq, int posoff, int use_rope){
  const int tg = blockIdx.x * 256 + threadIdx.x;
  const int n = tg % Nseq;
  const int bh = tg / Nseq;            // b*16 + h
  const short8* src = (const short8*)(qkv + ((size_t)(bh >> 4) * Nseq + n) * 3072 + (bh & 15) * 64);
  short8 qv[8], kv[8], vv[8];
  #pragma unroll
  for (int i=0;i<8;i++){ qv[i] = src[i]; kv[i] = src[i+128]; vv[i] = src[i+256]; }

  float qs=0.f, qss=0.f, ks=0.f, kss=0.f;
  #pragma unroll
  for (int i=0;i<8;i++){
    #pragma unroll
    for (int e=0;e<8;e++){
      float xq = bf2f(qv[i][e]); qs += xq; qss += xq*xq;
      float xk = bf2f(kv[i][e]); ks += xk; kss += xk*xk;
    }
  }
  const float qmu = qs * (1.f/64.f);
  const float qrv = rsqrtf(qss*(1.f/64.f) - qmu*qmu + 1e-5f);
  const float kmu = ks * (1.f/64.f);
  const float krv = rsqrtf(kss*(1.f/64.f) - kmu*kmu + 1e-5f);

  short8 qo[8], ko[8];
  if (use_rope){
    #pragma unroll
    for (int i=0;i<8;i++){
      #pragma unroll
      for (int e=0;e<8;e+=2){
        const int d = 4*i + (e>>1);
        const float cv = fcos[(size_t)n*32 + d];
        const float sv = fsin[(size_t)n*32 + d];
        const float xr = (bf2f(qv[i][e  ]) - qmu)*qrv*qw[8*i+e  ] + qb[8*i+e  ];
        const float xi = (bf2f(qv[i][e+1]) - qmu)*qrv*qw[8*i+e+1] + qb[8*i+e+1];
        qo[i][e  ] = f2bf((xr*cv - xi*sv) * QSCALE);
        qo[i][e+1] = f2bf((xr*sv + xi*cv) * QSCALE);
        const float yr = (bf2f(kv[i][e  ]) - kmu)*krv*kw[8*i+e  ] + kb[8*i+e  ];
        const float yi = (bf2f(kv[i][e+1]) - kmu)*krv*kw[8*i+e+1] + kb[8*i+e+1];
        ko[i][e  ] = f2bf(yr*cv - yi*sv);
        ko[i][e+1] = f2bf(yr*sv + yi*cv);
      }
    }
  } else {
    #pragma unroll
    for (int i=0;i<8;i++){
      #pragma unroll
      for (int e=0;e<8;e++){
        qo[i][e] = f2bf(((bf2f(qv[i][e]) - qmu)*qrv*qw[8*i+e] + qb[8*i+e]) * QSCALE);
        ko[i][e] = f2bf( (bf2f(kv[i][e]) - kmu)*krv*kw[8*i+e] + kb[8*i+e]);
      }
    }
  }
  short8* qd = (short8*)(Qo + ((size_t)bh * NT + posoff + n) * HD);
  short8* kd = (short8*)(Ko + ((size_t)bh * NT + posoff + n) * HD);
  short8* vd = (short8*)(Vo + ((size_t)bh * NT + posoff + n) * HD);
  #pragma unroll
  for (int i=0;i<8;i++){ qd[i] = qo[i]; kd[i] = ko[i]; vd[i] = vv[i]; }
}

// ---------------- V (B,H,NT,64) -> Vt (B,H,64,NT) ----------------
__global__ __launch_bounds__(256) void k_transpose_v(const short* __restrict__ V,
                                                     short* __restrict__ Vt){
  __shared__ short tl[64][72];
  const int blk = blockIdx.x;
  const int bh = blk / 36;
  const int n0 = (blk % 36) * 64;
  const int t = threadIdx.x, r = t >> 2, c = (t & 3) * 16;
  const short* src = V + ((size_t)bh * NT + n0 + r) * HD + c;
  short8 v0 = *(const short8*)(src);
  short8 v1 = *(const short8*)(src + 8);
  #pragma unroll
  for (int i=0;i<8;i++){ tl[r][c+i] = v0[i]; tl[r][c+8+i] = v1[i]; }
  __syncthreads();
  short8 o0, o1;
  #pragma unroll
  for (int i=0;i<8;i++){ o0[i] = tl[c+i][r]; o1[i] = tl[c+8+i][r]; }
  short* dst = Vt + ((size_t)bh * HD + r) * NT + n0 + c;
  *(short8*)dst       = o0;
  *(short8*)(dst + 8) = o1;
}

// ---------------- flash attention: QBLK=128, LDS-staged K/V ---------------
// 576 blocks = 32 bh x 18 q-tiles of 128 rows, XCD-chunked (blk&7 = XCD;
// 4 bh per XCD -> K/V L2-resident). 4 waves; wave w owns two 16-row sets:
// A = qt*128 + w*16 + lc, B = A + 64. Each tile staged once serves both
// sets (pass A then pass B = two copies of the round-6-verified pass).
// Defer-max (THR=8, exp2 domain): skip oacc rescale when max growth small.
__global__ __launch_bounds__(256) void k_attn(const short* __restrict__ Q,
                                              const short* __restrict__ Kg,
                                              const short* __restrict__ Vt,
                                              short* __restrict__ o1,
                                              short* __restrict__ o2){
  __shared__ __align__(16) short Kl[2][64][72];
  __shared__ __align__(16) short Vl[2][64][72];
  __shared__ __align__(16) short Ps[4][16][72];
  const int t = threadIdx.x, w = t >> 6, l = t & 63;
  const int lc = l & 15, g = l >> 4;
  const int blk = blockIdx.x;
  const int ch = blk & 7, i = blk >> 3;     // 576 = 8 * 72
  const int bh = ch * 4 + (i / 18);         // 4 bh per XCD-chunk
  const int qt = i % 18;
  const int b = bh >> 4, hh = bh & 15;
  const int q0 = qt * 128 + w * 16;
  const short* Qb = Q  + (size_t)bh * NT * HD;
  const short* Kb = Kg + (size_t)bh * NT * HD;
  const short* Vb = Vt + (size_t)bh * HD * NT;

  // Q fragments for both row-sets (B-operand: col q, k-elems g*8.. / +32)
  short8 qA0 = *(const short8*)(Qb + (size_t)(q0 + lc) * HD + g*8);
  short8 qA1 = *(const short8*)(Qb + (size_t)(q0 + lc) * HD + g*8 + 32);
  short8 qB0 = *(const short8*)(Qb + (size_t)(q0 + 64 + lc) * HD + g*8);
  short8 qB1 = *(const short8*)(Qb + (size_t)(q0 + 64 + lc) * HD + g*8 + 32);

  // staging role: row sr, 32B chunk at short-offset sc
  const int sr = t >> 2, sc = (t & 3) * 16;
  const short* Kgp = Kb + (size_t)sr * HD + sc;
  const short* Vgp = Vb + (size_t)sr * NT + sc;

  float mA = -1e30f, lA = 0.f, mB = -1e30f, lB = 0.f;
  f32x4 oA[4], oB[4];
  #pragma unroll
  for (int j=0;j<4;j++){
    oA[j][0]=0.f; oA[j][1]=0.f; oA[j][2]=0.f; oA[j][3]=0.f;
    oB[j][0]=0.f; oB[j][1]=0.f; oB[j][2]=0.f; oB[j][3]=0.f;
  }

  // prologue: stage tile 0 into buffer 0
  {
    short8 k0 = *(const short8*)(Kgp);
    short8 k1 = *(const short8*)(Kgp + 8);
    short8 v0 = *(const short8*)(Vgp);
    short8 v1 = *(const short8*)(Vgp + 8);
    *(short8*)&Kl[0][sr][sc]     = k0;
    *(short8*)&Kl[0][sr][sc + 8] = k1;
    *(short8*)&Vl[0][sr][sc]     = v0;
    *(short8*)&Vl[0][sr][sc + 8] = v1;
  }
  __syncthreads();

  for (int ti = 0; ti < 36; ++ti){
    const int cur = ti & 1;
    short8 kn0, kn1, vn0, vn1;
    if (ti < 35){
      const short* kp = Kgp + (size_t)(ti + 1) * 64 * HD;
      const short* vp = Vgp + (ti + 1) * 64;
      kn0 = *(const short8*)(kp);
      kn1 = *(const short8*)(kp + 8);
      vn0 = *(const short8*)(vp);
      vn1 = *(const short8*)(vp + 8);
    }

    // =================== pass A ===================
    {
      f32x4 s[4];
      __builtin_amdgcn_s_setprio(1);
      #pragma unroll
      for (int j=0;j<4;j++){
        const short* kp = &Kl[cur][j*16 + lc][g*8];
        short8 k0 = *(const short8*)(kp);
        short8 k1 = *(const short8*)(kp + 32);
        f32x4 a; a[0]=0.f; a[1]=0.f; a[2]=0.f; a[3]=0.f;
        a = __builtin_amdgcn_mfma_f32_16x16x32_bf16(k0, qA0, a, 0, 0, 0);
        a = __builtin_amdgcn_mfma_f32_16x16x32_bf16(k1, qA1, a, 0, 0, 0);
        s[j] = a;
      }
      __builtin_amdgcn_s_setprio(0);
      float t0 = fmaxf(fmaxf(s[0][0], s[0][1]), fmaxf(s[0][2], s[0][3]));
      float t1 = fmaxf(fmaxf(s[1][0], s[1][1]), fmaxf(s[1][2], s[1][3]));
      float t2 = fmaxf(fmaxf(s[2][0], s[2][1]), fmaxf(s[2][2], s[2][3]));
      float t3 = fmaxf(fmaxf(s[3][0], s[3][1]), fmaxf(s[3][2], s[3][3]));
      float tmx = fmaxf(fmaxf(t0, t1), fmaxf(t2, t3));
      tmx = fmaxf(tmx, __shfl_xor(tmx, 16, 64));
      tmx = fmaxf(tmx, __shfl_xor(tmx, 32, 64));
      float mn = mA;
      if (__any(tmx > mA + RESCALE_THR)){
        mn = fmaxf(mA, tmx);
        const float fsc = fexp2(mA - mn);
        mA = mn;
        lA *= fsc;
        #pragma unroll
        for (int j=0;j<4;j++){
          oA[j][0] *= fsc; oA[j][1] *= fsc; oA[j][2] *= fsc; oA[j][3] *= fsc;
        }
      }
      float p[4][4];
      #pragma unroll
      for (int j=0;j<4;j++){
        p[j][0] = fexp2(s[j][0] - mn);
        p[j][1] = fexp2(s[j][1] - mn);
        p[j][2] = fexp2(s[j][2] - mn);
        p[j][3] = fexp2(s[j][3] - mn);
      }
      float rs = ((p[0][0]+p[0][1])+(p[0][2]+p[0][3]))
               + ((p[1][0]+p[1][1])+(p[1][2]+p[1][3]))
               + ((p[2][0]+p[2][1])+(p[2][2]+p[2][3]))
               + ((p[3][0]+p[3][1])+(p[3][2]+p[3][3]));
      rs += __shfl_xor(rs, 16, 64);
      rs += __shfl_xor(rs, 32, 64);
      lA += rs;
      #pragma unroll
      for (int j=0;j<4;j++){
        unsigned int* dst = (unsigned int*)&Ps[w][lc][16*j + 4*g];
        dst[0] = pack2(f2bf(p[j][0]), f2bf(p[j][1]));
        dst[1] = pack2(f2bf(p[j][2]), f2bf(p[j][3]));
      }
      #pragma unroll
      for (int kk=0;kk<2;kk++){
        short8 pa = *(const short8*)(&Ps[w][lc][kk*32 + g*8]);
        __builtin_amdgcn_s_setprio(1);
        #pragma unroll
        for (int jd=0;jd<4;jd++){
          short8 vb = *(const short8*)(&Vl[cur][lc + 16*jd][kk*32 + g*8]);
          oA[jd] = __builtin_amdgcn_mfma_f32_16x16x32_bf16(vb, pa, oA[jd], 0, 0, 0);
        }
        __builtin_amdgcn_s_setprio(0);
      }
    }

    // =================== pass B ===================
    {
      f32x4 s[4];
      __builtin_amdgcn_s_setprio(1);
      #pragma unroll
      for (int j=0;j<4;j++){
        const short* kp = &Kl[cur][j*16 + lc][g*8];
        short8 k0 = *(const short8*)(kp);
        short8 k1 = *(const short8*)(kp + 32);
        f32x4 a; a[0]=0.f; a[1]=0.f; a[2]=0.f; a[3]=0.f;
        a = __builtin_amdgcn_mfma_f32_16x16x32_bf16(k0, qB0, a, 0, 0, 0);
        a = __builtin_amdgcn_mfma_f32_16x16x32_bf16(k1, qB1, a, 0, 0, 0);
        s[j] = a;
      }
      __builtin_amdgcn_s_setprio(0);
      float t0 = fmaxf(fmaxf(s[0][0], s[0][1]), fmaxf(s[0][2], s[0][3]));
      float t1 = fmaxf(fmaxf(s[1][0], s[1][1]), fmaxf(s[1][2], s[1][3]));
      float t2 = fmaxf(fmaxf(s[2][0], s[2][1]), fmaxf(s[2][2], s[2][3]));
      float t3 = fmaxf(fmaxf(s[3][0], s[3][1]), fmaxf(s[3][2], s[3][3]));
      float tmx = fmaxf(fmaxf(t0, t1), fmaxf(t2, t3));
      tmx = fmaxf(tmx, __shfl_xor(tmx, 16, 64));
      tmx = fmaxf(tmx, __shfl_xor(tmx, 32, 64));
      float mn = mB;
      if (__any(tmx > mB + RESCALE_THR)){
        mn = fmaxf(mB, tmx);
        const float fsc = fexp2(mB - mn);
        mB = mn;
        lB *= fsc;
        #pragma unroll
        for (int j=0;j<4;j++){
          oB[j][0] *= fsc; oB[j][1] *= fsc; oB[j][2] *= fsc; oB[j][3] *= fsc;
        }
      }
      float p[4][4];
      #pragma unroll
      for (int j=0;j<4;j++){
        p[j][0] = fexp2(s[j][0] - mn);
        p[j][1] = fexp2(s[j][1] - mn);
        p[j][2] = fexp2(s[j][2] - mn);
        p[j][3] = fexp2(s[j][3] - mn);
      }
      float rs = ((p[0][0]+p[0][1])+(p[0][2]+p[0][3]))
               + ((p[1][0]+p[1][1])+(p[1][2]+p[1][3]))
               + ((p[2][0]+p[2][1])+(p[2][2]+p[2][3]))
               + ((p[3][0]+p[3][1])+(p[3][2]+p[3][3]));
      rs += __shfl_xor(rs, 16, 64);
      rs += __shfl_xor(rs, 32, 64);
      lB += rs;
      #pragma unroll
      for (int j=0;j<4;j++){
        unsigned int* dst = (unsigned int*)&Ps[w][lc][16*j + 4*g];
        dst[0] = pack2(f2bf(p[j][0]), f2bf(p[j][1]));
        dst[1] = pack2(f2bf(p[j][2]), f2bf(p[j][3]));
      }
      #pragma unroll
      for (int kk=0;kk<2;kk++){
        short8 pa = *(const short8*)(&Ps[w][lc][kk*32 + g*8]);
        __builtin_amdgcn_s_setprio(1);
        #pragma unroll
        for (int jd=0;jd<4;jd++){
          short8 vb = *(const short8*)(&Vl[cur][lc + 16*jd][kk*32 + g*8]);
          oB[jd] = __builtin_amdgcn_mfma_f32_16x16x32_bf16(vb, pa, oB[jd], 0, 0, 0);
        }
        __builtin_amdgcn_s_setprio(0);
      }
    }

    if (ti < 35){
      *(short8*)&Kl[cur ^ 1][sr][sc]     = kn0;
      *(short8*)&Kl[cur ^ 1][sr][sc + 8] = kn1;
      *(short8*)&Vl[cur ^ 1][sr][sc]     = vn0;
      *(short8*)&Vl[cur ^ 1][sr][sc + 8] = vn1;
    }
    __syncthreads();
  }

  // ---- epilogue: normalize (lane-local) and write both sets ----
  {
    const float inv = 1.0f / lA;
    const int qi = q0 + lc;
    short* obase = (qi < N1) ? (o1 + ((size_t)b * N1 + qi) * D_)
                             : (o2 + ((size_t)b * N2 + (qi - N1)) * D_);
    #pragma unroll
    for (int jd=0;jd<4;jd++){
      bf4 ov;
      #pragma unroll
      for (int r=0;r<4;r++) ov[r] = f2bf(oA[jd][r] * inv);
      *(bf4*)(obase + hh*64 + 16*jd + 4*g) = ov;
    }
  }
  {
    const float inv = 1.0f / lB;
    const int qi = q0 + 64 + lc;
    short* obase = (qi < N1) ? (o1 + ((size_t)b * N1 + qi) * D_)
                             : (o2 + ((size_t)b * N2 + (qi - N1)) * D_);
    #pragma unroll
    for (int jd=0;jd<4;jd++){
      bf4 ov;
      #pragma unroll
      for (int r=0;r<4;r++) ov[r] = f2bf(oB[jd][r] * inv);
      *(bf4*)(obase + hh*64 + 16*jd + 4*g) = ov;
    }
  }
}

extern "C" void kernel_launch(void* const* d_in, const int* in_sizes, int n_in,
                              void* d_out, int out_size, void* d_ws, size_t ws_size,
                              hipStream_t stream){
  const float* x    = (const float*)d_in[0];
  const float* c    = (const float*)d_in[1];
  const float* fc   = (const float*)d_in[2];
  const float* fs   = (const float*)d_in[3];
  const float* Wq1  = (const float*)d_in[4];
  const float* bq1  = (const float*)d_in[5];
  const float* Wq2  = (const float*)d_in[6];
  const float* bq2  = (const float*)d_in[7];
  const float* qn1w = (const float*)d_in[8];
  const float* qn1b = (const float*)d_in[9];
  const float* kn1w = (const float*)d_in[10];
  const float* kn1b = (const float*)d_in[11];
  const float* qn2w = (const float*)d_in[12];
  const float* qn2b = (const float*)d_in[13];
  const float* kn2w = (const float*)d_in[14];
  const float* kn2b = (const float*)d_in[15];
  const float* Wp1  = (const float*)d_in[16];
  const float* bp1  = (const float*)d_in[17];
  const float* Wp2  = (const float*)d_in[18];
  const float* bp2  = (const float*)d_in[19];
  float* out = (float*)d_out;

  char* ws = (char*)d_ws;
  short* xb   = (short*)(ws);                       // 8,388,608
  short* cb   = (short*)(ws + 8388608);             // 1,048,576
  short* Wt1  = (short*)(ws + 9437184);             // 6,291,456
  short* Wt2  = (short*)(ws + 15728640);            // 6,291,456
  short* Wtp1 = (short*)(ws + 22020096);            // 2,097,152
  short* Wtp2 = (short*)(ws + 24117248);            // 2,097,152
  short* qkv1 = (short*)(ws + 26214400);            // 25,165,824 (bf16 4096x3072)
  short* qkv2 = (short*)(ws + 51380224);            // 3,145,728
  short* Qb   = (short*)(ws + 54525952);            // 9,437,184
  short* Kb   = (short*)(ws + 63963136);            // 9,437,184
  short* Vb   = (short*)(ws + 73400320);            // 9,437,184  -> total 82,837,504
  // aliases into qkv1 region (qkv1 fully consumed by k_lnrope before these are written)
  short* o1   = (short*)(ws + 26214400);            // 8,388,608
  short* o2   = (short*)(ws + 26214400 + 8388608);  // 1,048,576
  short* Vtb  = (short*)(ws + 26214400 + 9437184);  // 9,437,184

  k_cvt_bf16<<<2048, 256, 0, stream>>>(x, xb, 4194304);
  k_cvt_bf16<<<256, 256, 0, stream>>>(c, cb, 524288);
  k_transpose_w<<<dim3(48,16), 256, 0, stream>>>(Wq1, Wt1, 1024, 3072);
  k_transpose_w<<<dim3(48,16), 256, 0, stream>>>(Wq2, Wt2, 1024, 3072);
  k_transpose_w<<<dim3(16,16), 256, 0, stream>>>(Wp1, Wtp1, 1024, 1024);
  k_transpose_w<<<dim3(16,16), 256, 0, stream>>>(Wp2, Wtp2, 1024, 1024);

  k_gemm_bt<1><<<dim3(24,32), 256, 0, stream>>>(xb, Wt1, bq1, qkv1, 4096, 3072, 1024);
  k_gemm_bt<1><<<dim3(24,4),  256, 0, stream>>>(cb, Wt2, bq2, qkv2,  512, 3072, 1024);

  k_lnrope<<<256, 256, 0, stream>>>(qkv1, qn1w, qn1b, kn1w, kn1b, fc, fs, Qb, Kb, Vb, 2048, 0, 1);
  k_lnrope<<<32,  256, 0, stream>>>(qkv2, qn2w, qn2b, kn2w, kn2b, fc, fs, Qb, Kb, Vb,  256, 2048, 0);

  k_transpose_v<<<1152, 256, 0, stream>>>(Vb, Vtb);
  k_attn<<<576, 256, 0, stream>>>(Qb, Kb, Vtb, o1, o2);

  k_gemm_bt<0><<<dim3(8,32), 256, 0, stream>>>(o1, Wtp1, bp1, out,           4096, 1024, 1024);
  k_gemm_bt<0><<<dim3(8,4),  256, 0, stream>>>(o2, Wtp2, bp2, out + 4194304,  512, 1024, 1024);
}

// Round 8
// 221.968 us; speedup vs baseline: 1.3290x; 1.3290x over previous
//
#include <hip/hip_runtime.h>
#include <hip/hip_bf16.h>
#include <stdint.h>

typedef __attribute__((ext_vector_type(8))) short short8;
typedef __attribute__((ext_vector_type(4))) short bf4;
typedef __attribute__((ext_vector_type(4))) float f32x4;

#define B_ 2
#define N1 2048
#define N2 256
#define NT 2304
#define D_ 1024
#define H_ 16
#define HD 64
// attention scale folded into Q: hd^-0.5 * log2(e)
#define QSCALE 0.18033688011112042f
#define RESCALE_THR 8.0f

static __device__ __forceinline__ float bf2f(short s){
  union { unsigned int u; float f; } u;
  u.u = ((unsigned int)(unsigned short)s) << 16;
  return u.f;
}
// round-to-nearest-even f32 -> bf16 (finite inputs)
static __device__ __forceinline__ short f2bf(float f){
  union { float f; unsigned int u; } v; v.f = f;
  unsigned int u = v.u;
  unsigned int lsb = (u >> 16) & 1u;
  u += 0x7fffu + lsb;
  return (short)(u >> 16);
}
// packed f32x2 -> bf16x2 via compiler (v_cvt_pk_bf16_f32), RNE
static __device__ __forceinline__ unsigned int cvtpk2(float a, float b){
  union { __hip_bfloat162 h; unsigned int u; } cv;
  cv.h = __float22bfloat162_rn(make_float2(a, b));
  return cv.u;
}

static __device__ __forceinline__ float fexp2(float x){
#if __has_builtin(__builtin_amdgcn_exp2f)
  return __builtin_amdgcn_exp2f(x);
#else
  return exp2f(x);
#endif
}

static __device__ __forceinline__ void gload16(const void* g, void* l){
  __builtin_amdgcn_global_load_lds(
      (const __attribute__((address_space(1))) void*)g,
      (__attribute__((address_space(3))) void*)l, 16, 0, 0);
}

// swizzled short-index into a [64 rows][8 chunks of 8 shorts] LDS tile
static __device__ __forceinline__ int swz(int row, int chunk){
  return (row << 6) + ((chunk ^ (row & 7)) << 3);
}

// ---------------- fp32 -> bf16 convert (x and c fused; outputs contiguous) --
__global__ __launch_bounds__(256) void k_cvt_all(const float* __restrict__ x,
                                                 const float* __restrict__ c,
                                                 short* __restrict__ out){
  int i = (blockIdx.x * 256 + threadIdx.x) * 8;
  const float* in = (i < 4194304) ? (x + i) : (c + (i - 4194304));
  float4 a = *(const float4*)(in);
  float4 b = *(const float4*)(in + 4);
  short8 o;
  o[0]=f2bf(a.x); o[1]=f2bf(a.y); o[2]=f2bf(a.z); o[3]=f2bf(a.w);
  o[4]=f2bf(b.x); o[5]=f2bf(b.y); o[6]=f2bf(b.z); o[7]=f2bf(b.w);
  *(short8*)(out + i) = o;
}

// ---------------- W (K x N, f32) -> Wt (N x K, bf16), 4 matrices fused -----
__global__ __launch_bounds__(256) void k_transpose_w4(
    const float* __restrict__ Wq1, const float* __restrict__ Wq2,
    const float* __restrict__ Wp1, const float* __restrict__ Wp2,
    short* __restrict__ Wt1, short* __restrict__ Wt2,
    short* __restrict__ Wtp1, short* __restrict__ Wtp2){
  const int id = blockIdx.x;
  const float* W; short* Wt; int N; int bx, by;
  if (id < 768)      { W = Wq1; Wt = Wt1;  N = 3072; bx = id % 48;          by = id / 48; }
  else if (id < 1536){ W = Wq2; Wt = Wt2;  N = 3072; bx = (id-768) % 48;    by = (id-768) / 48; }
  else if (id < 1792){ W = Wp1; Wt = Wtp1; N = 1024; bx = (id-1536) % 16;   by = (id-1536) / 16; }
  else               { W = Wp2; Wt = Wtp2; N = 1024; bx = (id-1792) % 16;   by = (id-1792) / 16; }
  const int K = 1024;
  __shared__ float tl[64][65];
  const int n0 = bx * 64, k0 = by * 64;
  const int t = threadIdx.x, r = t >> 2, c = (t & 3) * 16;
  const float* src = W + (size_t)(k0 + r) * N + n0 + c;
  #pragma unroll
  for (int i = 0; i < 16; i += 4){
    float4 v = *(const float4*)(src + i);
    tl[r][c+i] = v.x; tl[r][c+i+1] = v.y; tl[r][c+i+2] = v.z; tl[r][c+i+3] = v.w;
  }
  __syncthreads();
  short8 o0, o1;
  #pragma unroll
  for (int i = 0; i < 8; i++) o0[i] = f2bf(tl[c+i][r]);
  #pragma unroll
  for (int i = 0; i < 8; i++) o1[i] = f2bf(tl[c+8+i][r]);
  short* dst = Wt + (size_t)(n0 + r) * K + k0 + c;
  *(short8*)(dst)     = o0;
  *(short8*)(dst + 8) = o1;
}

// ---------------- GEMM: C[M,N] = A[M,K] * Bt[N,K]^T + bias ----------------
// m97-style 128x128 tile; XCD-chunked block map (grid blocks % 8 == 0);
// rows >= Msplit use Bt2/bias2 (fused second GEMM on contiguous A/C).
template<int OUT_BF16>
__global__ __launch_bounds__(256) void k_gemm_bt(const short* __restrict__ A,
                                                 const short* __restrict__ Bt,
                                                 const short* __restrict__ Bt2,
                                                 const float* __restrict__ bias,
                                                 const float* __restrict__ bias2,
                                                 void* __restrict__ Cp,
                                                 int N, int K, int Msplit){
  __shared__ __align__(16) short As[128*32];
  __shared__ __align__(16) short Bs[128*32];
  const int t = threadIdx.x;
  const int w = t >> 6, l = t & 63;
  const int lc = l & 15, g = l >> 4;
  // bijective XCD chunking: consecutive nbid within one XCD share A-row panels
  const int gx = gridDim.x;
  const int nb = gx * gridDim.y;
  const int bid = blockIdx.y * gx + blockIdx.x;
  const int nbid = (bid & 7) * (nb >> 3) + (bid >> 3);
  const int tm = (nbid / gx) * 128, tn = (nbid % gx) * 128;
  const int wm = (w >> 1) * 64, wn = (w & 1) * 64;

  const short* Bsel = (tm < Msplit) ? Bt : Bt2;
  const float* bsel = (tm < Msplit) ? bias : bias2;

  const int r0 = w*32 + (l >> 2);
  const int r1 = r0 + 16;
  const int cb = (l & 3) * 16;

  const char* Ag0 = (const char*)(A + (size_t)(tm + r0) * K) + cb;
  const char* Ag1 = (const char*)(A + (size_t)(tm + r1) * K) + cb;
  const char* Bg0 = (const char*)(Bsel + (size_t)(tn + r0) * K) + cb;
  const char* Bg1 = (const char*)(Bsel + (size_t)(tn + r1) * K) + cb;
  char* Al0 = (char*)As + (w*2  )*1024;
  char* Al1 = (char*)As + (w*2+1)*1024;
  char* Bl0 = (char*)Bs + (w*2  )*1024;
  char* Bl1 = (char*)Bs + (w*2+1)*1024;

  f32x4 acc[4][4];
  #pragma unroll
  for (int m=0;m<4;m++){
    #pragma unroll
    for (int n=0;n<4;n++){ acc[m][n][0]=0.f; acc[m][n][1]=0.f; acc[m][n][2]=0.f; acc[m][n][3]=0.f; }
  }

  for (int k0 = 0; k0 < K; k0 += 32){
    const int kb = k0 * 2;
    gload16(Ag0 + kb, Al0);
    gload16(Ag1 + kb, Al1);
    gload16(Bg0 + kb, Bl0);
    gload16(Bg1 + kb, Bl1);
    __syncthreads();
    short8 af[4], bfr[4];
    #pragma unroll
    for (int m=0;m<4;m++) af[m]  = *(const short8*)(As + (wm + m*16 + lc)*32 + g*8);
    #pragma unroll
    for (int n=0;n<4;n++) bfr[n] = *(const short8*)(Bs + (wn + n*16 + lc)*32 + g*8);
    #pragma unroll
    for (int m=0;m<4;m++){
      #pragma unroll
      for (int n=0;n<4;n++)
        acc[m][n] = __builtin_amdgcn_mfma_f32_16x16x32_bf16(af[m], bfr[n], acc[m][n], 0, 0, 0);
    }
    __syncthreads();
  }

  #pragma unroll
  for (int n=0;n<4;n++){
    const int col = tn + wn + n*16 + lc;
    const float bv = bsel[col];
    #pragma unroll
    for (int m=0;m<4;m++){
      const int row = tm + wm + m*16 + g*4;
      #pragma unroll
      for (int r=0;r<4;r++){
        float v = acc[m][n][r] + bv;
        if (OUT_BF16) ((short*)Cp)[(size_t)(row + r)*N + col] = f2bf(v);
        else          ((float*)Cp)[(size_t)(row + r)*N + col] = v;
      }
    }
  }
}

// ---------------- per-head LN (+ optional RoPE), split QKV (wave/row) -----
__global__ __launch_bounds__(256) void k_lnrope(const short* __restrict__ qkv,
    const float* __restrict__ qw, const float* __restrict__ qb,
    const float* __restrict__ kw, const float* __restrict__ kb,
    const float* __restrict__ fcos, const float* __restrict__ fsin,
    short* __restrict__ Qo, short* __restrict__ Ko, short* __restrict__ Vo,
    int Nseq, int posoff, int use_rope){
  const int wv = (blockIdx.x * 256 + threadIdx.x) >> 6;
  const int l = threadIdx.x & 63;
  const int h = wv % H_;
  const int n = (wv / H_) % Nseq;
  const int b = wv / (H_ * Nseq);
  const size_t ibase = ((size_t)(b * Nseq + n)) * 3072 + h * 64 + l;
  float q = bf2f(qkv[ibase]);
  float k = bf2f(qkv[ibase + 1024]);
  short v = qkv[ibase + 2048];

  float mu = q;
  #pragma unroll
  for (int mk = 1; mk < 64; mk <<= 1) mu += __shfl_xor(mu, mk, 64);
  mu *= (1.f/64.f);
  float dq = q - mu;
  float var = dq * dq;
  #pragma unroll
  for (int mk = 1; mk < 64; mk <<= 1) var += __shfl_xor(var, mk, 64);
  var *= (1.f/64.f);
  float qn = dq * rsqrtf(var + 1e-5f) * qw[l] + qb[l];

  float muk = k;
  #pragma unroll
  for (int mk = 1; mk < 64; mk <<= 1) muk += __shfl_xor(muk, mk, 64);
  muk *= (1.f/64.f);
  float dk = k - muk;
  float vark = dk * dk;
  #pragma unroll
  for (int mk = 1; mk < 64; mk <<= 1) vark += __shfl_xor(vark, mk, 64);
  vark *= (1.f/64.f);
  float kn = dk * rsqrtf(vark + 1e-5f) * kw[l] + kb[l];

  if (use_rope){
    float cv = fcos[(size_t)n * 32 + (l >> 1)];
    float sv = fsin[(size_t)n * 32 + (l >> 1)];
    float qp = __shfl_xor(qn, 1, 64);
    float kp = __shfl_xor(kn, 1, 64);
    qn = (l & 1) ? (qp * sv + qn * cv) : (qn * cv - qp * sv);
    kn = (l & 1) ? (kp * sv + kn * cv) : (kn * cv - kp * sv);
  }
  qn *= QSCALE;
  const size_t obase = ((size_t)(b * H_ + h) * NT + posoff + n) * HD + l;
  Qo[obase] = f2bf(qn);
  Ko[obase] = f2bf(kn);
  Vo[obase] = v;
}

// ---------------- V (B,H,NT,64) -> Vt (B,H,64,NT) ----------------
__global__ __launch_bounds__(256) void k_transpose_v(const short* __restrict__ V,
                                                     short* __restrict__ Vt){
  __shared__ short tl[64][72];
  const int blk = blockIdx.x;
  const int bh = blk / 36;
  const int n0 = (blk % 36) * 64;
  const int t = threadIdx.x, r = t >> 2, c = (t & 3) * 16;
  const short* src = V + ((size_t)bh * NT + n0 + r) * HD + c;
  short8 v0 = *(const short8*)(src);
  short8 v1 = *(const short8*)(src + 8);
  #pragma unroll
  for (int i=0;i<8;i++){ tl[r][c+i] = v0[i]; tl[r][c+8+i] = v1[i]; }
  __syncthreads();
  short8 o0, o1;
  #pragma unroll
  for (int i=0;i<8;i++){ o0[i] = tl[c+i][r]; o1[i] = tl[c+8+i][r]; }
  short* dst = Vt + ((size_t)bh * HD + r) * NT + n0 + c;
  *(short8*)dst       = o0;
  *(short8*)(dst + 8) = o1;
}

// ---------------- flash attention: r6 structure, 40KB swizzled LDS --------
// 1152 blocks = 32 bh x 36 q-tiles, XCD-chunked. 4 waves share the 64-row
// Q tile; 36 KV tiles of 64, double-buffered. K/V/P tiles use XOR chunk
// swizzle (chunk ^= row&7) in unpadded [64][64] layout -> LDS = 40960 B
// exactly = 4 blocks/CU. Defer-max + packed P conversion.
__global__ __launch_bounds__(256) void k_attn(const short* __restrict__ Q,
                                              const short* __restrict__ Kg,
                                              const short* __restrict__ Vt,
                                              short* __restrict__ o1,
                                              short* __restrict__ o2){
  __shared__ __align__(16) short Kl[2][4096];
  __shared__ __align__(16) short Vl[2][4096];
  __shared__ __align__(16) short Ps[4][1024];
  const int t = threadIdx.x, w = t >> 6, l = t & 63;
  const int lc = l & 15, g = l >> 4;
  const int blk = blockIdx.x;
  const int ch = blk & 7, ii = blk >> 3;    // 1152 = 8 * 144
  const int bh = ch * 4 + (ii / 36);        // 4 bh per XCD-chunk
  const int qt = ii % 36;
  const int b = bh >> 4, hh = bh & 15;
  const int q0 = qt * 64 + w * 16;
  const short* Qb = Q  + (size_t)bh * NT * HD;
  const short* Kb = Kg + (size_t)bh * NT * HD;
  const short* Vb = Vt + (size_t)bh * HD * NT;

  // Q fragment (B-operand): col q=lc, k-elems = head-dims g*8.. / +32
  short8 qf0 = *(const short8*)(Qb + (size_t)(q0 + lc) * HD + g*8);
  short8 qf1 = *(const short8*)(Qb + (size_t)(q0 + lc) * HD + g*8 + 32);

  // staging role: row sr, chunks c0=(t&3)*2, c0+1 (32B per thread per tile)
  const int sr = t >> 2, c0 = (t & 3) * 2;
  const short* Kgp = Kb + (size_t)sr * HD + c0 * 8;
  const short* Vgp = Vb + (size_t)sr * NT + c0 * 8;
  const int w0 = swz(sr, c0), w1 = swz(sr, c0 + 1);

  float mcur = -1e30f, lcur = 0.f;
  f32x4 oacc[4];
  #pragma unroll
  for (int j=0;j<4;j++){ oacc[j][0]=0.f; oacc[j][1]=0.f; oacc[j][2]=0.f; oacc[j][3]=0.f; }

  // prologue: stage tile 0 into buffer 0
  {
    short8 k0 = *(const short8*)(Kgp);
    short8 k1 = *(const short8*)(Kgp + 8);
    short8 v0 = *(const short8*)(Vgp);
    short8 v1 = *(const short8*)(Vgp + 8);
    *(short8*)&Kl[0][w0] = k0;
    *(short8*)&Kl[0][w1] = k1;
    *(short8*)&Vl[0][w0] = v0;
    *(short8*)&Vl[0][w1] = v1;
  }
  __syncthreads();

  for (int ti = 0; ti < 36; ++ti){
    const int cur = ti & 1;
    // issue next tile's global loads early (hide latency under compute)
    short8 kn0, kn1, vn0, vn1;
    if (ti < 35){
      const short* kp = Kgp + (size_t)(ti + 1) * 64 * HD;
      const short* vp = Vgp + (ti + 1) * 64;
      kn0 = *(const short8*)(kp);
      kn1 = *(const short8*)(kp + 8);
      vn0 = *(const short8*)(vp);
      vn1 = *(const short8*)(vp + 8);
    }
    // ---- S^T: s[j][r] = S[q=lc][kv = ti*64 + 16j + 4g + r] ----
    f32x4 s[4];
    __builtin_amdgcn_s_setprio(1);
    #pragma unroll
    for (int j=0;j<4;j++){
      const int row = j*16 + lc;
      short8 k0 = *(const short8*)(&Kl[cur][swz(row, g)]);
      short8 k1 = *(const short8*)(&Kl[cur][swz(row, g + 4)]);
      f32x4 a; a[0]=0.f; a[1]=0.f; a[2]=0.f; a[3]=0.f;
      a = __builtin_amdgcn_mfma_f32_16x16x32_bf16(k0, qf0, a, 0, 0, 0);
      a = __builtin_amdgcn_mfma_f32_16x16x32_bf16(k1, qf1, a, 0, 0, 0);
      s[j] = a;
    }
    __builtin_amdgcn_s_setprio(0);
    // ---- lane-local softmax for q-row lc ----
    float t0 = fmaxf(fmaxf(s[0][0], s[0][1]), fmaxf(s[0][2], s[0][3]));
    float t1 = fmaxf(fmaxf(s[1][0], s[1][1]), fmaxf(s[1][2], s[1][3]));
    float t2 = fmaxf(fmaxf(s[2][0], s[2][1]), fmaxf(s[2][2], s[2][3]));
    float t3 = fmaxf(fmaxf(s[3][0], s[3][1]), fmaxf(s[3][2], s[3][3]));
    float tmx = fmaxf(fmaxf(t0, t1), fmaxf(t2, t3));
    tmx = fmaxf(tmx, __shfl_xor(tmx, 16, 64));
    tmx = fmaxf(tmx, __shfl_xor(tmx, 32, 64));
    float mn = mcur;
    if (__any(tmx > mcur + RESCALE_THR)){
      mn = fmaxf(mcur, tmx);
      const float fsc = fexp2(mcur - mn);
      mcur = mn;
      lcur *= fsc;
      #pragma unroll
      for (int j=0;j<4;j++){
        oacc[j][0] *= fsc; oacc[j][1] *= fsc; oacc[j][2] *= fsc; oacc[j][3] *= fsc;
      }
    }
    float p[4][4];
    #pragma unroll
    for (int j=0;j<4;j++){
      p[j][0] = fexp2(s[j][0] - mn);
      p[j][1] = fexp2(s[j][1] - mn);
      p[j][2] = fexp2(s[j][2] - mn);
      p[j][3] = fexp2(s[j][3] - mn);
    }
    float rs = ((p[0][0]+p[0][1])+(p[0][2]+p[0][3]))
             + ((p[1][0]+p[1][1])+(p[1][2]+p[1][3]))
             + ((p[2][0]+p[2][1])+(p[2][2]+p[2][3]))
             + ((p[3][0]+p[3][1])+(p[3][2]+p[3][3]));
    rs += __shfl_xor(rs, 16, 64);
    rs += __shfl_xor(rs, 32, 64);
    lcur += rs;
    // ---- P -> LDS (swizzled): row q=lc, cols 16j+4g+{0..3} ----
    #pragma unroll
    for (int j=0;j<4;j++){
      const int si = (lc << 6) + (((2*j + (g >> 1)) ^ (lc & 7)) << 3) + (g & 1) * 4;
      unsigned int* dst = (unsigned int*)&Ps[w][si];
      dst[0] = cvtpk2(p[j][0], p[j][1]);
      dst[1] = cvtpk2(p[j][2], p[j][3]);
    }
    // ---- PV swapped: oacc[jd] = mfma(V^T rows d, P^T cols q) ----
    #pragma unroll
    for (int kk=0;kk<2;kk++){
      short8 pa = *(const short8*)(&Ps[w][swz(lc, 4*kk + g)]);
      __builtin_amdgcn_s_setprio(1);
      #pragma unroll
      for (int jd=0;jd<4;jd++){
        short8 vb = *(const short8*)(&Vl[cur][swz(lc + 16*jd, 4*kk + g)]);
        oacc[jd] = __builtin_amdgcn_mfma_f32_16x16x32_bf16(vb, pa, oacc[jd], 0, 0, 0);
      }
      __builtin_amdgcn_s_setprio(0);
    }
    // ---- write next tile into the other buffer, then sync ----
    if (ti < 35){
      *(short8*)&Kl[cur ^ 1][w0] = kn0;
      *(short8*)&Kl[cur ^ 1][w1] = kn1;
      *(short8*)&Vl[cur ^ 1][w0] = vn0;
      *(short8*)&Vl[cur ^ 1][w1] = vn1;
    }
    __syncthreads();
  }

  // ---- epilogue: normalize (lane-local) and write ----
  const float inv = 1.0f / lcur;
  const int qi = q0 + lc;
  short* obase = (qi < N1) ? (o1 + ((size_t)b * N1 + qi) * D_)
                           : (o2 + ((size_t)b * N2 + (qi - N1)) * D_);
  #pragma unroll
  for (int jd=0;jd<4;jd++){
    bf4 ov;
    #pragma unroll
    for (int r=0;r<4;r++) ov[r] = f2bf(oacc[jd][r] * inv);
    *(bf4*)(obase + hh*64 + 16*jd + 4*g) = ov;
  }
}

extern "C" void kernel_launch(void* const* d_in, const int* in_sizes, int n_in,
                              void* d_out, int out_size, void* d_ws, size_t ws_size,
                              hipStream_t stream){
  const float* x    = (const float*)d_in[0];
  const float* c    = (const float*)d_in[1];
  const float* fc   = (const float*)d_in[2];
  const float* fs   = (const float*)d_in[3];
  const float* Wq1  = (const float*)d_in[4];
  const float* bq1  = (const float*)d_in[5];
  const float* Wq2  = (const float*)d_in[6];
  const float* bq2  = (const float*)d_in[7];
  const float* qn1w = (const float*)d_in[8];
  const float* qn1b = (const float*)d_in[9];
  const float* kn1w = (const float*)d_in[10];
  const float* kn1b = (const float*)d_in[11];
  const float* qn2w = (const float*)d_in[12];
  const float* qn2b = (const float*)d_in[13];
  const float* kn2w = (const float*)d_in[14];
  const float* kn2b = (const float*)d_in[15];
  const float* Wp1  = (const float*)d_in[16];
  const float* bp1  = (const float*)d_in[17];
  const float* Wp2  = (const float*)d_in[18];
  const float* bp2  = (const float*)d_in[19];
  float* out = (float*)d_out;

  char* ws = (char*)d_ws;
  short* xb   = (short*)(ws);                       // 8,388,608 (xb+cb contiguous)
  short* Wt1  = (short*)(ws + 9437184);             // 6,291,456
  short* Wt2  = (short*)(ws + 15728640);            // 6,291,456
  short* Wtp1 = (short*)(ws + 22020096);            // 2,097,152
  short* Wtp2 = (short*)(ws + 24117248);            // 2,097,152
  short* qkv1 = (short*)(ws + 26214400);            // 25,165,824 (+qkv2 contiguous)
  short* qkv2 = (short*)(ws + 51380224);            // 3,145,728
  short* Qb   = (short*)(ws + 54525952);            // 9,437,184
  short* Kb   = (short*)(ws + 63963136);            // 9,437,184
  short* Vb   = (short*)(ws + 73400320);            // 9,437,184  -> total 82,837,504
  // aliases into qkv1 region (qkv1 fully consumed by k_lnrope before these are written)
  short* o1   = (short*)(ws + 26214400);            // 8,388,608 (o1+o2 contiguous)
  short* Vtb  = (short*)(ws + 26214400 + 9437184);  // 9,437,184

  k_cvt_all<<<2304, 256, 0, stream>>>(x, c, xb);
  k_transpose_w4<<<2048, 256, 0, stream>>>(Wq1, Wq2, Wp1, Wp2, Wt1, Wt2, Wtp1, Wtp2);

  // fused QKV GEMM: A = [xb; cb] (4608 x 1024), rows >= 4096 use Wt2/bq2
  k_gemm_bt<1><<<dim3(24,36), 256, 0, stream>>>(xb, Wt1, Wt2, bq1, bq2, qkv1, 3072, 1024, 4096);

  k_lnrope<<<16384, 256, 0, stream>>>(qkv1, qn1w, qn1b, kn1w, kn1b, fc, fs, Qb, Kb, Vb, 2048, 0, 1);
  k_lnrope<<<2048,  256, 0, stream>>>(qkv2, qn2w, qn2b, kn2w, kn2b, fc, fs, Qb, Kb, Vb,  256, 2048, 0);

  k_transpose_v<<<1152, 256, 0, stream>>>(Vb, Vtb);
  k_attn<<<1152, 256, 0, stream>>>(Qb, Kb, Vtb, o1, o1 + 4194304);

  // fused projection GEMM: A = [o1; o2] (4608 x 1024), rows >= 4096 use Wtp2/bp2
  k_gemm_bt<0><<<dim3(8,36), 256, 0, stream>>>(o1, Wtp1, Wtp2, bp1, bp2, out, 1024, 1024, 4096);
}